// Round 5
// baseline (2013.185 us; speedup 1.0000x reference)
//
#include <hip/hip_runtime.h>

// ---------------------------------------------------------------------------
// EncoderLayer: S=1024, B=4, D=1024, H=16, dh=64, DFF=4096.
// R4 finding: inputs AND output are fp32 (reference dtypes). Intermediates
// staged in bf16 workspace for bandwidth; accumulation in fp32.
//
// Index algebra (quadruple-audited):
//  * proj reshape is flat-transparent: Q[b,h,s,d] = Y[(b*1024+s)*1024 + h*64+d]
//    where Y rows are x's (s*4+b) row order.
//  * skew(emd)[s,t] = emd[s, t-s+1023] if t<=s else 0
//  * softmax over BATCH dim (4 values per (h,s,t))
//  * attn_out (S,B,D) = O (B,H,S,dh) flat-reinterpreted; row m=(s*4+b) matches x.
//
// Workspace map (224 MB):
//  [0,16M)    O      f32   [16M,24M) Yq bf16  [24M,32M) Yk  [32M,40M) Yv
//  [40M,48M)  h1 bf16  [48M,80M) ffn1 bf16  [80M,96M) ffn2 f32
//  [96M,224M) scores bf16 (softmaxed in place)
// ---------------------------------------------------------------------------

typedef unsigned short u16;
typedef unsigned int u32;

__device__ __forceinline__ float bf2f(u16 u) { return __uint_as_float(((u32)u) << 16); }
__device__ __forceinline__ u16 f2bf(float f) {
    u32 u = __float_as_uint(f);
    u += 0x7fffu + ((u >> 16) & 1u);   // RNE
    return (u16)(u >> 16);
}
__device__ __forceinline__ void unpack8(uint4 v, float* f) {
    f[0] = __uint_as_float(v.x << 16); f[1] = __uint_as_float(v.x & 0xffff0000u);
    f[2] = __uint_as_float(v.y << 16); f[3] = __uint_as_float(v.y & 0xffff0000u);
    f[4] = __uint_as_float(v.z << 16); f[5] = __uint_as_float(v.z & 0xffff0000u);
    f[6] = __uint_as_float(v.w << 16); f[7] = __uint_as_float(v.w & 0xffff0000u);
}
// load 8 consecutive elements at flat index idx (mult of 8). DT: 0=bf16, 1=f32
template<int DT>
__device__ __forceinline__ void load8(const void* P, size_t idx, float* f) {
    if (DT == 0) { uint4 v = *(const uint4*)((const u16*)P + idx); unpack8(v, f); }
    else {
        const float* p = (const float*)P + idx;
        float4 a = *(const float4*)p, b = *(const float4*)(p + 4);
        f[0] = a.x; f[1] = a.y; f[2] = a.z; f[3] = a.w;
        f[4] = b.x; f[5] = b.y; f[6] = b.z; f[7] = b.w;
    }
}
template<int DT>
__device__ __forceinline__ float load1(const void* P, size_t idx) {
    return (DT == 0) ? bf2f(((const u16*)P)[idx]) : ((const float*)P)[idx];
}

__global__ __launch_bounds__(256) void sentinel_ws(float* out, u32 n)
{
    for (u32 i = blockIdx.x * 256 + threadIdx.x; i < n; i += gridDim.x * 256) out[i] = 31000.0f;
}

// ---------------- C[M,N] = act(A[M,K] @ B[N,K]^T + bias) -------------------
// 128x128 tile, 256 threads, 8x8 microtile, BK=16.
template<int RELU, int OUT_F32, int DTA, int DTB>
__global__ __launch_bounds__(256) void gemm_bt(
    const void* __restrict__ A, const void* __restrict__ B,
    const float* __restrict__ bias, void* __restrict__ Cout,
    int M, int N, int K)
{
    __shared__ __align__(16) float As[16][132];
    __shared__ __align__(16) float Bs[16][132];
    const int tid = threadIdx.x;
    const int m0 = blockIdx.y << 7;
    const int n0 = blockIdx.x << 7;
    const int ty = tid >> 4, tx = tid & 15;
    const int lr = tid >> 1;
    const int lc = (tid & 1) << 3;

    float acc[8][8];
#pragma unroll
    for (int i = 0; i < 8; i++)
#pragma unroll
        for (int j = 0; j < 8; j++) acc[i][j] = 0.f;

    const size_t arow = (size_t)(m0 + lr) * K + lc;
    const size_t brow = (size_t)(n0 + lr) * K + lc;

    for (int k0 = 0; k0 < K; k0 += 16) {
        float af[8], bfv[8];
        load8<DTA>(A, arow + k0, af);
        load8<DTB>(B, brow + k0, bfv);
        __syncthreads();
#pragma unroll
        for (int i = 0; i < 8; i++) { As[lc + i][lr] = af[i]; Bs[lc + i][lr] = bfv[i]; }
        __syncthreads();
#pragma unroll
        for (int k = 0; k < 16; k++) {
            float a[8], b[8];
            *(float4*)&a[0] = *(const float4*)&As[k][ty * 8];
            *(float4*)&a[4] = *(const float4*)&As[k][ty * 8 + 4];
            *(float4*)&b[0] = *(const float4*)&Bs[k][tx * 8];
            *(float4*)&b[4] = *(const float4*)&Bs[k][tx * 8 + 4];
#pragma unroll
            for (int i = 0; i < 8; i++)
#pragma unroll
                for (int j = 0; j < 8; j++) acc[i][j] = fmaf(a[i], b[j], acc[i][j]);
        }
    }

    float bb[8];
#pragma unroll
    for (int j = 0; j < 8; j++) bb[j] = bias ? bias[n0 + tx * 8 + j] : 0.f;

#pragma unroll
    for (int i = 0; i < 8; i++) {
        const int m = m0 + ty * 8 + i;
        float o[8];
#pragma unroll
        for (int j = 0; j < 8; j++) {
            float v = acc[i][j] + bb[j];
            o[j] = RELU ? fmaxf(v, 0.f) : v;
        }
        if (OUT_F32) {
            float* C = (float*)Cout;
            float4 w0, w1;
            w0.x = o[0]; w0.y = o[1]; w0.z = o[2]; w0.w = o[3];
            w1.x = o[4]; w1.y = o[5]; w1.z = o[6]; w1.w = o[7];
            *(float4*)(C + (size_t)m * N + n0 + tx * 8) = w0;
            *(float4*)(C + (size_t)m * N + n0 + tx * 8 + 4) = w1;
        } else {
            u16* C = (u16*)Cout;
            uint4 pk;
            pk.x = (u32)f2bf(o[0]) | ((u32)f2bf(o[1]) << 16);
            pk.y = (u32)f2bf(o[2]) | ((u32)f2bf(o[3]) << 16);
            pk.z = (u32)f2bf(o[4]) | ((u32)f2bf(o[5]) << 16);
            pk.w = (u32)f2bf(o[6]) | ((u32)f2bf(o[7]) << 16);
            *(uint4*)(C + (size_t)m * N + n0 + tx * 8) = pk;
        }
    }
}

// ------- scores[b,h,s,t] = QK^T/8 + (t<=s ? emd[s, t-s+1023] : 0) ----------
// Yq/Yk are ws bf16; relw is fp32 input.
__global__ __launch_bounds__(256) void qk_skew(
    const u16* __restrict__ Yq, const u16* __restrict__ Yk,
    const float* __restrict__ relw, u16* __restrict__ scores)
{
    __shared__ __align__(16) float Qs[64][68];
    __shared__ __align__(16) float Ks[64][68];
    __shared__ __align__(16) u16   Rs[64][136];   // 272B row = 17*16
    const int tid = threadIdx.x;
    const int bh = blockIdx.z, b = bh >> 4, h = bh & 15;
    const int s0 = blockIdx.y << 6, t0 = blockIdx.x << 6;
    const int skew_mode = (t0 < s0) ? 2 : ((t0 == s0) ? 1 : 0);
    const int u0 = t0 - s0 + 960;

    {
        const int r = tid >> 2;
        const int dq = (tid & 3) << 4;
        const u16* qp = Yq + (size_t)(b * 1024 + s0 + r) * 1024 + h * 64 + dq;
        const u16* kp = Yk + (size_t)(b * 1024 + t0 + r) * 1024 + h * 64 + dq;
        uint4 q0 = *(const uint4*)qp, q1 = *(const uint4*)(qp + 8);
        uint4 k0 = *(const uint4*)kp, k1 = *(const uint4*)(kp + 8);
        float f0[8], f1[8], g0[8], g1[8];
        unpack8(q0, f0); unpack8(q1, f1); unpack8(k0, g0); unpack8(k1, g1);
#pragma unroll
        for (int i = 0; i < 8; i++) {
            Qs[dq + i][r] = f0[i]; Qs[dq + 8 + i][r] = f1[i];
            Ks[dq + i][r] = g0[i]; Ks[dq + 8 + i][r] = g1[i];
        }
    }
    if (skew_mode) {
        const int d = tid >> 2;
        const int jb = (tid & 3) << 5;
#pragma unroll
        for (int g = 0; g < 4; g++) {
            const int j = jb + (g << 3);
            const int u = u0 + j;                 // mult of 8 (u0 mult of 64)
            uint4 v;
            if (u < 1024) {
                const float* rp = relw + (size_t)bh * 65536 + (size_t)d * 1024 + u;
                float4 a = *(const float4*)rp, bq = *(const float4*)(rp + 4);
                v.x = (u32)f2bf(a.x) | ((u32)f2bf(a.y) << 16);
                v.y = (u32)f2bf(a.z) | ((u32)f2bf(a.w) << 16);
                v.z = (u32)f2bf(bq.x) | ((u32)f2bf(bq.y) << 16);
                v.w = (u32)f2bf(bq.z) | ((u32)f2bf(bq.w) << 16);
            } else { v.x = 0; v.y = 0; v.z = 0; v.w = 0; }
            *(uint4*)&Rs[d][j] = v;
        }
    }
    __syncthreads();

    const int ty = tid >> 4, tx = tid & 15;
    float aqk[4][4], ae[4][4];
#pragma unroll
    for (int i = 0; i < 4; i++)
#pragma unroll
        for (int j = 0; j < 4; j++) { aqk[i][j] = 0.f; ae[i][j] = 0.f; }
    const int j0 = (tx - ty) * 4 + 60;           // in [0,120], mult of 4

    for (int d = 0; d < 64; d++) {
        float q[4], k[4];
        *(float4*)q = *(const float4*)&Qs[d][ty * 4];
        *(float4*)k = *(const float4*)&Ks[d][tx * 4];
#pragma unroll
        for (int si = 0; si < 4; si++)
#pragma unroll
            for (int ti = 0; ti < 4; ti++) aqk[si][ti] = fmaf(q[si], k[ti], aqk[si][ti]);
        if (skew_mode) {
            uint2 ra = *(const uint2*)&Rs[d][j0];
            uint2 rb = *(const uint2*)&Rs[d][j0 + 4];
            float r[8];
            r[0] = __uint_as_float(ra.x << 16); r[1] = __uint_as_float(ra.x & 0xffff0000u);
            r[2] = __uint_as_float(ra.y << 16); r[3] = __uint_as_float(ra.y & 0xffff0000u);
            r[4] = __uint_as_float(rb.x << 16); r[5] = __uint_as_float(rb.x & 0xffff0000u);
            r[6] = __uint_as_float(rb.y << 16); r[7] = __uint_as_float(rb.y & 0xffff0000u);
#pragma unroll
            for (int si = 0; si < 4; si++)
#pragma unroll
                for (int ti = 0; ti < 4; ti++) ae[si][ti] = fmaf(q[si], r[ti - si + 3], ae[si][ti]);
        }
    }

#pragma unroll
    for (int si = 0; si < 4; si++) {
        const int s = s0 + ty * 4 + si;
        float v[4];
#pragma unroll
        for (int ti = 0; ti < 4; ti++) {
            const int t = t0 + tx * 4 + ti;
            float e = 0.f;
            if (skew_mode == 2) e = ae[si][ti];
            else if (skew_mode == 1 && t <= s) e = ae[si][ti];
            v[ti] = aqk[si][ti] * 0.125f + e;
        }
        uint2 pk;
        pk.x = (u32)f2bf(v[0]) | ((u32)f2bf(v[1]) << 16);
        pk.y = (u32)f2bf(v[2]) | ((u32)f2bf(v[3]) << 16);
        *(uint2*)(scores + ((size_t)bh * 1024 + s) * 1024 + t0 + tx * 4) = pk;
    }
}

// ---------------- softmax over batch dim (4 values), in place --------------
__global__ __launch_bounds__(256) void softmax_b(u16* __restrict__ sc)
{
    const size_t e = ((size_t)blockIdx.x * 256 + threadIdx.x) * 2;
    const size_t bs = (size_t)16 * 1024 * 1024;
    float x[4][2];
#pragma unroll
    for (int b = 0; b < 4; b++) {
        u32 v = *(const u32*)(sc + b * bs + e);
        x[b][0] = __uint_as_float(v << 16);
        x[b][1] = __uint_as_float(v & 0xffff0000u);
    }
#pragma unroll
    for (int sl = 0; sl < 2; sl++) {
        float m = fmaxf(fmaxf(x[0][sl], x[1][sl]), fmaxf(x[2][sl], x[3][sl]));
        float ex[4], s = 0.f;
#pragma unroll
        for (int b = 0; b < 4; b++) { ex[b] = __expf(x[b][sl] - m); s += ex[b]; }
        float inv = 1.f / s;
#pragma unroll
        for (int b = 0; b < 4; b++) x[b][sl] = ex[b] * inv;
    }
#pragma unroll
    for (int b = 0; b < 4; b++) {
        u32 v = (u32)f2bf(x[b][0]) | ((u32)f2bf(x[b][1]) << 16);
        *(u32*)(sc + b * bs + e) = v;
    }
}

// ------------- O[b,h,s,d] = sum_t attn[b,h,s,t] * V[b,h,t,d] ---------------
__global__ __launch_bounds__(256) void pv_gemm(
    const u16* __restrict__ attn, const u16* __restrict__ Yv, float* __restrict__ O)
{
    __shared__ __align__(16) float Ps[32][68];
    __shared__ __align__(16) float Vs[32][68];
    const int tid = threadIdx.x;
    const int bh = blockIdx.y, b = bh >> 4, h = bh & 15;
    const int s0 = blockIdx.x << 6;
    const int ty = tid >> 4, tx = tid & 15;
    const int pr = tid >> 2, pq = (tid & 3) << 3;
    const int vr = tid >> 3, vq = (tid & 7) << 3;

    float acc[4][4];
#pragma unroll
    for (int i = 0; i < 4; i++)
#pragma unroll
        for (int j = 0; j < 4; j++) acc[i][j] = 0.f;

    for (int t0 = 0; t0 < 1024; t0 += 32) {
        uint4 pa = *(const uint4*)(attn + ((size_t)bh * 1024 + s0 + pr) * 1024 + t0 + pq);
        uint4 va = *(const uint4*)(Yv + (size_t)(b * 1024 + t0 + vr) * 1024 + h * 64 + vq);
        float pf[8], vf[8];
        unpack8(pa, pf); unpack8(va, vf);
        __syncthreads();
#pragma unroll
        for (int i = 0; i < 8; i++) Ps[pq + i][pr] = pf[i];
        float4 w0, w1;
        w0.x = vf[0]; w0.y = vf[1]; w0.z = vf[2]; w0.w = vf[3];
        w1.x = vf[4]; w1.y = vf[5]; w1.z = vf[6]; w1.w = vf[7];
        *(float4*)&Vs[vr][vq] = w0;
        *(float4*)&Vs[vr][vq + 4] = w1;
        __syncthreads();
#pragma unroll
        for (int k = 0; k < 32; k++) {
            float a[4], v[4];
            *(float4*)a = *(const float4*)&Ps[k][ty * 4];
            *(float4*)v = *(const float4*)&Vs[k][tx * 4];
#pragma unroll
            for (int si = 0; si < 4; si++)
#pragma unroll
                for (int di = 0; di < 4; di++) acc[si][di] = fmaf(a[si], v[di], acc[si][di]);
        }
    }
#pragma unroll
    for (int si = 0; si < 4; si++) {
        float4 w;
        w.x = acc[si][0]; w.y = acc[si][1]; w.z = acc[si][2]; w.w = acc[si][3];
        *(float4*)(O + ((size_t)bh * 1024 + s0 + ty * 4 + si) * 64 + tx * 4) = w;
    }
}

// ------------- out = LN(A + f32 B) * g + beta ------------------------------
// A dtype DTA (0=bf16 ws, 1=f32); g/beta f32; out f32 or bf16.
template<int DTA, int OUT_F32>
__global__ __launch_bounds__(256) void add_ln(
    const void* __restrict__ A, const float* __restrict__ Bf,
    const float* __restrict__ g, const float* __restrict__ beta,
    void* __restrict__ out)
{
    const int row = blockIdx.x;
    const int tid = threadIdx.x;
    const size_t base = (size_t)row * 1024;
    float v[4], s1 = 0.f, s2 = 0.f;
#pragma unroll
    for (int k = 0; k < 4; k++) {
        const int c = k * 256 + tid;
        float t = load1<DTA>(A, base + c) + Bf[base + c];
        v[k] = t; s1 += t; s2 += t * t;
    }
#pragma unroll
    for (int m = 1; m < 64; m <<= 1) {
        s1 += __shfl_xor(s1, m, 64);
        s2 += __shfl_xor(s2, m, 64);
    }
    __shared__ float red[8];
    if ((tid & 63) == 0) { red[(tid >> 6) * 2] = s1; red[(tid >> 6) * 2 + 1] = s2; }
    __syncthreads();
    s1 = red[0] + red[2] + red[4] + red[6];
    s2 = red[1] + red[3] + red[5] + red[7];
    const float mean = s1 * (1.f / 1024.f);
    const float var = s2 * (1.f / 1024.f) - mean * mean;
    const float rstd = rsqrtf(var + 1e-5f);
#pragma unroll
    for (int k = 0; k < 4; k++) {
        const int c = k * 256 + tid;
        float o = (v[k] - mean) * rstd * g[c] + beta[c];
        if (OUT_F32) ((float*)out)[base + c] = o;
        else ((u16*)out)[base + c] = f2bf(o);
    }
}

// ---------------------------------------------------------------------------
extern "C" void kernel_launch(void* const* d_in, const int* in_sizes, int n_in,
                              void* d_out, int out_size, void* d_ws, size_t ws_size,
                              hipStream_t stream)
{
    const float* x    = (const float*)d_in[0];
    const float* wq   = (const float*)d_in[1];
    const float* wk   = (const float*)d_in[2];
    const float* wv   = (const float*)d_in[3];
    const float* relw = (const float*)d_in[4];
    const float* g1   = (const float*)d_in[5];
    const float* be1  = (const float*)d_in[6];
    const float* g2   = (const float*)d_in[7];
    const float* be2  = (const float*)d_in[8];
    const float* w1   = (const float*)d_in[9];
    const float* b1   = (const float*)d_in[10];
    const float* w2   = (const float*)d_in[11];
    const float* b2   = (const float*)d_in[12];

    const size_t NEEDED = ((size_t)224 << 20);
    if (ws_size < NEEDED) {
        sentinel_ws<<<dim3(1024), dim3(256), 0, stream>>>((float*)d_out, (u32)out_size);
        return;
    }

    char* ws = (char*)d_ws;
    float* O     = (float*)(ws);
    u16*   Yq    = (u16*)(ws + ((size_t)16 << 20));
    u16*   Yk    = (u16*)(ws + ((size_t)24 << 20));
    u16*   Yv    = (u16*)(ws + ((size_t)32 << 20));
    u16*   h1    = (u16*)(ws + ((size_t)40 << 20));
    u16*   ffn1  = (u16*)(ws + ((size_t)48 << 20));
    float* ffn2  = (float*)(ws + ((size_t)80 << 20));
    u16*   sc    = (u16*)(ws + ((size_t)96 << 20));

    dim3 blk(256);
    // QKV projections: Y = X @ W^T (f32 in, bf16 out)
    gemm_bt<0,0,1,1><<<dim3(8,32), blk, 0, stream>>>(x, wq, nullptr, Yq, 4096, 1024, 1024);
    gemm_bt<0,0,1,1><<<dim3(8,32), blk, 0, stream>>>(x, wk, nullptr, Yk, 4096, 1024, 1024);
    gemm_bt<0,0,1,1><<<dim3(8,32), blk, 0, stream>>>(x, wv, nullptr, Yv, 4096, 1024, 1024);
    // scores + rel-pos skew
    qk_skew<<<dim3(16,16,64), blk, 0, stream>>>(Yq, Yk, relw, sc);
    // softmax over batch dim
    softmax_b<<<dim3(32768), blk, 0, stream>>>(sc);
    // attn @ V
    pv_gemm<<<dim3(16,64), blk, 0, stream>>>(sc, Yv, O);
    // h1 = LN(x + attn_out)  (x f32, O f32 -> h1 bf16)
    add_ln<1,0><<<dim3(4096), blk, 0, stream>>>(x, O, g1, be1, h1);
    // FFN
    gemm_bt<1,0,0,1><<<dim3(32,32), blk, 0, stream>>>(h1, w1, b1, ffn1, 4096, 4096, 1024);
    gemm_bt<0,1,0,1><<<dim3(8,32), blk, 0, stream>>>(ffn1, w2, b2, ffn2, 4096, 1024, 4096);
    // out = LN(h1 + ffn)  -> f32 d_out
    add_ln<0,1><<<dim3(4096), blk, 0, stream>>>(h1, ffn2, g2, be2, (float*)d_out);
}

// Round 8
// 838.317 us; speedup vs baseline: 2.4015x; 2.4015x over previous
//
#include <hip/hip_runtime.h>

// ---------------------------------------------------------------------------
// EncoderLayer: S=1024, B=4, D=1024, H=16, dh=64, DFF=4096. fp32 I/O.
// R7: MFMA GEMMs with PLAIN per-lane staging (no global_load_lds, no raw
// s_waitcnt builtins) — R6's async-DMA variant killed the container twice;
// isolating the MFMA math from the async staging machinery.
//
// Index algebra (verified by R5 pass):
//  * Q[b,h,s,d] = Y[(b*1024+s)*1024 + h*64+d], Y rows in (s*4+b) order
//  * skew(emd)[s,t] = emd[s, t-s+1023] if t<=s else 0
//  * softmax over BATCH dim; attn_out row m=(s*4+b) matches x rows
//
// Workspace map (224 MB):
//  [0,16M)    O f32   [16M,24M) Yq bf16  [24M,32M) Yk  [32M,40M) Yv
//  [40M,48M)  h1 bf16  [48M,80M) ffn1 bf16  [80M,96M) ffn2 f32
//  [96M,224M) scores bf16 (softmaxed in place)
//    overlap (pre-qk):  xb@96M(8MB) wqb@104M wkb@106M wvb@108M
//    overlap (post-pv): w1b@96M(8MB) w2b@104M(8MB)
// ---------------------------------------------------------------------------

typedef unsigned short u16;
typedef unsigned int u32;
typedef __attribute__((ext_vector_type(4))) float f32x4;
typedef __attribute__((ext_vector_type(8))) short bf16x8;

__device__ __forceinline__ float bf2f(u16 u) { return __uint_as_float(((u32)u) << 16); }
__device__ __forceinline__ u16 f2bf(float f) {
    u32 u = __float_as_uint(f);
    u += 0x7fffu + ((u >> 16) & 1u);   // RNE
    return (u16)(u >> 16);
}
__device__ __forceinline__ void unpack8(uint4 v, float* f) {
    f[0] = __uint_as_float(v.x << 16); f[1] = __uint_as_float(v.x & 0xffff0000u);
    f[2] = __uint_as_float(v.y << 16); f[3] = __uint_as_float(v.y & 0xffff0000u);
    f[4] = __uint_as_float(v.z << 16); f[5] = __uint_as_float(v.z & 0xffff0000u);
    f[6] = __uint_as_float(v.w << 16); f[7] = __uint_as_float(v.w & 0xffff0000u);
}
template<int DT>
__device__ __forceinline__ float load1(const void* P, size_t idx) {
    return (DT == 0) ? bf2f(((const u16*)P)[idx]) : ((const float*)P)[idx];
}

__global__ __launch_bounds__(256) void sentinel_ws(float* out, u32 n)
{
    for (u32 i = blockIdx.x * 256 + threadIdx.x; i < n; i += gridDim.x * 256) out[i] = 31000.0f;
}

// ---------------- fp32 -> bf16 bulk convert (n mult of 4) ------------------
__global__ __launch_bounds__(256) void cvt_f32_bf16(const float* __restrict__ s,
                                                    u16* __restrict__ d, u32 n)
{
    u32 i = (blockIdx.x * 256 + threadIdx.x) * 4;
    if (i >= n) return;
    float4 v = *(const float4*)(s + i);
    uint2 pk;
    pk.x = (u32)f2bf(v.x) | ((u32)f2bf(v.y) << 16);
    pk.y = (u32)f2bf(v.z) | ((u32)f2bf(v.w) << 16);
    *(uint2*)(d + i) = pk;
}

// --------------- MFMA GEMM: C[M,N] = act(A[M,K] @ B[N,K]^T + bias) ---------
// A,B bf16 row-major K-contiguous. 128x128 tile, BK=32, 256 thr (4 waves),
// each wave 64x64 via 4x4 mfma_f32_16x16x32_bf16.
// LDS layout: row r (0..127) occupies 32 u16 at As[r*32], stored as 4 chunks
// of 8; logical k-chunk l lives at physical slot p = l ^ ((r>>1)&3) (XOR
// swizzle -> 2-way bank aliasing on ds_read_b128, free per m136).
// Staging: thread tid covers row r0=tid>>2 (+64), physical slot tid&3, so its
// global source chunk is (tid&3)^((r0>>1)&3); LDS dest = As + tid*8 (+2048).
template<int RELU, int OUT_F32, int HAS_BIAS>
__global__ __launch_bounds__(256) void mfma_gemm(
    const u16* __restrict__ A, const u16* __restrict__ B,
    const float* __restrict__ bias, void* __restrict__ Cout,
    int M, int N, int K)
{
    __shared__ __align__(16) u16 As[4096];   // 128 rows x 32
    __shared__ __align__(16) u16 Bs[4096];
    const int tid = threadIdx.x;
    const int wave = tid >> 6, lane = tid & 63;
    const int quad = lane >> 4, l16 = lane & 15;
    const int m0 = blockIdx.y << 7, n0 = blockIdx.x << 7;
    const int wm = (wave >> 1) << 6, wn = (wave & 1) << 6;

    const int r0 = tid >> 2;                      // 0..63
    const int csw = ((tid & 3) ^ ((r0 >> 1) & 3)) << 3;
    const u16* Ag0 = A + (size_t)(m0 + r0) * K + csw;
    const u16* Ag1 = A + (size_t)(m0 + r0 + 64) * K + csw;
    const u16* Bg0 = B + (size_t)(n0 + r0) * K + csw;
    const u16* Bg1 = B + (size_t)(n0 + r0 + 64) * K + csw;

    f32x4 acc[4][4];
#pragma unroll
    for (int i = 0; i < 4; i++)
#pragma unroll
        for (int j = 0; j < 4; j++) acc[i][j] = (f32x4){0.f, 0.f, 0.f, 0.f};

    const int pb = ((quad ^ ((l16 >> 1) & 3)) << 3);   // reader swizzle

    for (int k0 = 0; k0 < K; k0 += 32) {
        uint4 a0 = *(const uint4*)(Ag0 + k0);
        uint4 a1 = *(const uint4*)(Ag1 + k0);
        uint4 b0 = *(const uint4*)(Bg0 + k0);
        uint4 b1 = *(const uint4*)(Bg1 + k0);
        __syncthreads();                         // prev-tile reads complete
        *(uint4*)(As + tid * 8)        = a0;
        *(uint4*)(As + 2048 + tid * 8) = a1;
        *(uint4*)(Bs + tid * 8)        = b0;
        *(uint4*)(Bs + 2048 + tid * 8) = b1;
        __syncthreads();                         // publish

        bf16x8 af[4], bfr[4];
#pragma unroll
        for (int mi = 0; mi < 4; mi++)
            af[mi] = *(const bf16x8*)(As + ((wm + mi * 16 + l16) << 5) + pb);
#pragma unroll
        for (int ni = 0; ni < 4; ni++)
            bfr[ni] = *(const bf16x8*)(Bs + ((wn + ni * 16 + l16) << 5) + pb);
#pragma unroll
        for (int mi = 0; mi < 4; mi++)
#pragma unroll
            for (int ni = 0; ni < 4; ni++)
                acc[mi][ni] = __builtin_amdgcn_mfma_f32_16x16x32_bf16(
                    af[mi], bfr[ni], acc[mi][ni], 0, 0, 0);
    }

    float bb[4];
#pragma unroll
    for (int ni = 0; ni < 4; ni++)
        bb[ni] = HAS_BIAS ? bias[n0 + wn + ni * 16 + l16] : 0.f;

#pragma unroll
    for (int mi = 0; mi < 4; mi++) {
#pragma unroll
        for (int ni = 0; ni < 4; ni++) {
            const int col = n0 + wn + ni * 16 + l16;
#pragma unroll
            for (int r = 0; r < 4; r++) {
                const int row = m0 + wm + mi * 16 + quad * 4 + r;
                float v = acc[mi][ni][r] + bb[ni];
                if (RELU) v = fmaxf(v, 0.f);
                if (OUT_F32) ((float*)Cout)[(size_t)row * N + col] = v;
                else ((u16*)Cout)[(size_t)row * N + col] = f2bf(v);
            }
        }
    }
}

// ------- scores[b,h,s,t] = QK^T/8 + (t<=s ? emd[s, t-s+1023] : 0) ----------
__global__ __launch_bounds__(256) void qk_skew(
    const u16* __restrict__ Yq, const u16* __restrict__ Yk,
    const float* __restrict__ relw, u16* __restrict__ scores)
{
    __shared__ __align__(16) float Qs[64][68];
    __shared__ __align__(16) float Ks[64][68];
    __shared__ __align__(16) u16   Rs[64][136];
    const int tid = threadIdx.x;
    const int bh = blockIdx.z, b = bh >> 4, h = bh & 15;
    const int s0 = blockIdx.y << 6, t0 = blockIdx.x << 6;
    const int skew_mode = (t0 < s0) ? 2 : ((t0 == s0) ? 1 : 0);
    const int u0 = t0 - s0 + 960;

    {
        const int r = tid >> 2;
        const int dq = (tid & 3) << 4;
        const u16* qp = Yq + (size_t)(b * 1024 + s0 + r) * 1024 + h * 64 + dq;
        const u16* kp = Yk + (size_t)(b * 1024 + t0 + r) * 1024 + h * 64 + dq;
        uint4 q0 = *(const uint4*)qp, q1 = *(const uint4*)(qp + 8);
        uint4 k0 = *(const uint4*)kp, k1 = *(const uint4*)(kp + 8);
        float f0[8], f1[8], g0[8], g1[8];
        unpack8(q0, f0); unpack8(q1, f1); unpack8(k0, g0); unpack8(k1, g1);
#pragma unroll
        for (int i = 0; i < 8; i++) {
            Qs[dq + i][r] = f0[i]; Qs[dq + 8 + i][r] = f1[i];
            Ks[dq + i][r] = g0[i]; Ks[dq + 8 + i][r] = g1[i];
        }
    }
    if (skew_mode) {
        const int d = tid >> 2;
        const int jb = (tid & 3) << 5;
#pragma unroll
        for (int g = 0; g < 4; g++) {
            const int j = jb + (g << 3);
            const int u = u0 + j;
            uint4 v;
            if (u < 1024) {
                const float* rp = relw + (size_t)bh * 65536 + (size_t)d * 1024 + u;
                float4 a = *(const float4*)rp, bq = *(const float4*)(rp + 4);
                v.x = (u32)f2bf(a.x) | ((u32)f2bf(a.y) << 16);
                v.y = (u32)f2bf(a.z) | ((u32)f2bf(a.w) << 16);
                v.z = (u32)f2bf(bq.x) | ((u32)f2bf(bq.y) << 16);
                v.w = (u32)f2bf(bq.z) | ((u32)f2bf(bq.w) << 16);
            } else { v.x = 0; v.y = 0; v.z = 0; v.w = 0; }
            *(uint4*)&Rs[d][j] = v;
        }
    }
    __syncthreads();

    const int ty = tid >> 4, tx = tid & 15;
    float aqk[4][4], ae[4][4];
#pragma unroll
    for (int i = 0; i < 4; i++)
#pragma unroll
        for (int j = 0; j < 4; j++) { aqk[i][j] = 0.f; ae[i][j] = 0.f; }
    const int j0 = (tx - ty) * 4 + 60;

    for (int d = 0; d < 64; d++) {
        float q[4], k[4];
        *(float4*)q = *(const float4*)&Qs[d][ty * 4];
        *(float4*)k = *(const float4*)&Ks[d][tx * 4];
#pragma unroll
        for (int si = 0; si < 4; si++)
#pragma unroll
            for (int ti = 0; ti < 4; ti++) aqk[si][ti] = fmaf(q[si], k[ti], aqk[si][ti]);
        if (skew_mode) {
            uint2 ra = *(const uint2*)&Rs[d][j0];
            uint2 rb = *(const uint2*)&Rs[d][j0 + 4];
            float r[8];
            r[0] = __uint_as_float(ra.x << 16); r[1] = __uint_as_float(ra.x & 0xffff0000u);
            r[2] = __uint_as_float(ra.y << 16); r[3] = __uint_as_float(ra.y & 0xffff0000u);
            r[4] = __uint_as_float(rb.x << 16); r[5] = __uint_as_float(rb.x & 0xffff0000u);
            r[6] = __uint_as_float(rb.y << 16); r[7] = __uint_as_float(rb.y & 0xffff0000u);
#pragma unroll
            for (int si = 0; si < 4; si++)
#pragma unroll
                for (int ti = 0; ti < 4; ti++) ae[si][ti] = fmaf(q[si], r[ti - si + 3], ae[si][ti]);
        }
    }

#pragma unroll
    for (int si = 0; si < 4; si++) {
        const int s = s0 + ty * 4 + si;
        float v[4];
#pragma unroll
        for (int ti = 0; ti < 4; ti++) {
            const int t = t0 + tx * 4 + ti;
            float e = 0.f;
            if (skew_mode == 2) e = ae[si][ti];
            else if (skew_mode == 1 && t <= s) e = ae[si][ti];
            v[ti] = aqk[si][ti] * 0.125f + e;
        }
        uint2 pk;
        pk.x = (u32)f2bf(v[0]) | ((u32)f2bf(v[1]) << 16);
        pk.y = (u32)f2bf(v[2]) | ((u32)f2bf(v[3]) << 16);
        *(uint2*)(scores + ((size_t)bh * 1024 + s) * 1024 + t0 + tx * 4) = pk;
    }
}

// ---------------- softmax over batch dim (4 values), in place --------------
__global__ __launch_bounds__(256) void softmax_b(u16* __restrict__ sc)
{
    const size_t e = ((size_t)blockIdx.x * 256 + threadIdx.x) * 2;
    const size_t bs = (size_t)16 * 1024 * 1024;
    float x[4][2];
#pragma unroll
    for (int b = 0; b < 4; b++) {
        u32 v = *(const u32*)(sc + b * bs + e);
        x[b][0] = __uint_as_float(v << 16);
        x[b][1] = __uint_as_float(v & 0xffff0000u);
    }
#pragma unroll
    for (int sl = 0; sl < 2; sl++) {
        float m = fmaxf(fmaxf(x[0][sl], x[1][sl]), fmaxf(x[2][sl], x[3][sl]));
        float ex[4], s = 0.f;
#pragma unroll
        for (int b = 0; b < 4; b++) { ex[b] = __expf(x[b][sl] - m); s += ex[b]; }
        float inv = 1.f / s;
#pragma unroll
        for (int b = 0; b < 4; b++) x[b][sl] = ex[b] * inv;
    }
#pragma unroll
    for (int b = 0; b < 4; b++) {
        u32 v = (u32)f2bf(x[b][0]) | ((u32)f2bf(x[b][1]) << 16);
        *(u32*)(sc + b * bs + e) = v;
    }
}

// ------------- O[b,h,s,d] = sum_t attn[b,h,s,t] * V[b,h,t,d] ---------------
__global__ __launch_bounds__(256) void pv_gemm(
    const u16* __restrict__ attn, const u16* __restrict__ Yv, float* __restrict__ O)
{
    __shared__ __align__(16) float Ps[32][68];
    __shared__ __align__(16) float Vs[32][68];
    const int tid = threadIdx.x;
    const int bh = blockIdx.y, b = bh >> 4, h = bh & 15;
    const int s0 = blockIdx.x << 6;
    const int ty = tid >> 4, tx = tid & 15;
    const int pr = tid >> 2, pq = (tid & 3) << 3;
    const int vr = tid >> 3, vq = (tid & 7) << 3;

    float acc[4][4];
#pragma unroll
    for (int i = 0; i < 4; i++)
#pragma unroll
        for (int j = 0; j < 4; j++) acc[i][j] = 0.f;

    for (int t0 = 0; t0 < 1024; t0 += 32) {
        uint4 pa = *(const uint4*)(attn + ((size_t)bh * 1024 + s0 + pr) * 1024 + t0 + pq);
        uint4 va = *(const uint4*)(Yv + (size_t)(b * 1024 + t0 + vr) * 1024 + h * 64 + vq);
        float pf[8], vf[8];
        unpack8(pa, pf); unpack8(va, vf);
        __syncthreads();
#pragma unroll
        for (int i = 0; i < 8; i++) Ps[pq + i][pr] = pf[i];
        float4 w0, w1;
        w0.x = vf[0]; w0.y = vf[1]; w0.z = vf[2]; w0.w = vf[3];
        w1.x = vf[4]; w1.y = vf[5]; w1.z = vf[6]; w1.w = vf[7];
        *(float4*)&Vs[vr][vq] = w0;
        *(float4*)&Vs[vr][vq + 4] = w1;
        __syncthreads();
#pragma unroll
        for (int k = 0; k < 32; k++) {
            float a[4], v[4];
            *(float4*)a = *(const float4*)&Ps[k][ty * 4];
            *(float4*)v = *(const float4*)&Vs[k][tx * 4];
#pragma unroll
            for (int si = 0; si < 4; si++)
#pragma unroll
                for (int di = 0; di < 4; di++) acc[si][di] = fmaf(a[si], v[di], acc[si][di]);
        }
    }
#pragma unroll
    for (int si = 0; si < 4; si++) {
        float4 w;
        w.x = acc[si][0]; w.y = acc[si][1]; w.z = acc[si][2]; w.w = acc[si][3];
        *(float4*)(O + ((size_t)bh * 1024 + s0 + ty * 4 + si) * 64 + tx * 4) = w;
    }
}

// ------------- out = LN(A + f32 B) * g + beta ------------------------------
template<int DTA, int OUT_F32>
__global__ __launch_bounds__(256) void add_ln(
    const void* __restrict__ A, const float* __restrict__ Bf,
    const float* __restrict__ g, const float* __restrict__ beta,
    void* __restrict__ out)
{
    const int row = blockIdx.x;
    const int tid = threadIdx.x;
    const size_t base = (size_t)row * 1024;
    float v[4], s1 = 0.f, s2 = 0.f;
#pragma unroll
    for (int k = 0; k < 4; k++) {
        const int c = k * 256 + tid;
        float t = load1<DTA>(A, base + c) + Bf[base + c];
        v[k] = t; s1 += t; s2 += t * t;
    }
#pragma unroll
    for (int m = 1; m < 64; m <<= 1) {
        s1 += __shfl_xor(s1, m, 64);
        s2 += __shfl_xor(s2, m, 64);
    }
    __shared__ float red[8];
    if ((tid & 63) == 0) { red[(tid >> 6) * 2] = s1; red[(tid >> 6) * 2 + 1] = s2; }
    __syncthreads();
    s1 = red[0] + red[2] + red[4] + red[6];
    s2 = red[1] + red[3] + red[5] + red[7];
    const float mean = s1 * (1.f / 1024.f);
    const float var = s2 * (1.f / 1024.f) - mean * mean;
    const float rstd = rsqrtf(var + 1e-5f);
#pragma unroll
    for (int k = 0; k < 4; k++) {
        const int c = k * 256 + tid;
        float o = (v[k] - mean) * rstd * g[c] + beta[c];
        if (OUT_F32) ((float*)out)[base + c] = o;
        else ((u16*)out)[base + c] = f2bf(o);
    }
}

// ---------------------------------------------------------------------------
extern "C" void kernel_launch(void* const* d_in, const int* in_sizes, int n_in,
                              void* d_out, int out_size, void* d_ws, size_t ws_size,
                              hipStream_t stream)
{
    const float* x    = (const float*)d_in[0];
    const float* wq   = (const float*)d_in[1];
    const float* wk   = (const float*)d_in[2];
    const float* wv   = (const float*)d_in[3];
    const float* relw = (const float*)d_in[4];
    const float* g1   = (const float*)d_in[5];
    const float* be1  = (const float*)d_in[6];
    const float* g2   = (const float*)d_in[7];
    const float* be2  = (const float*)d_in[8];
    const float* w1   = (const float*)d_in[9];
    const float* b1   = (const float*)d_in[10];
    const float* w2   = (const float*)d_in[11];
    const float* b2   = (const float*)d_in[12];

    const size_t NEEDED = ((size_t)224 << 20);
    if (ws_size < NEEDED) {
        sentinel_ws<<<dim3(1024), dim3(256), 0, stream>>>((float*)d_out, (u32)out_size);
        return;
    }

    char* ws = (char*)d_ws;
    float* O     = (float*)(ws);
    u16*   Yq    = (u16*)(ws + ((size_t)16 << 20));
    u16*   Yk    = (u16*)(ws + ((size_t)24 << 20));
    u16*   Yv    = (u16*)(ws + ((size_t)32 << 20));
    u16*   h1    = (u16*)(ws + ((size_t)40 << 20));
    u16*   ffn1  = (u16*)(ws + ((size_t)48 << 20));
    float* ffn2  = (float*)(ws + ((size_t)80 << 20));
    u16*   sc    = (u16*)(ws + ((size_t)96 << 20));
    // lifetime-overlapped bf16 staging inside the scores region:
    u16*   xb    = (u16*)(ws + ((size_t)96 << 20));             // pre-qk
    u16*   wqb   = (u16*)(ws + ((size_t)104 << 20));
    u16*   wkb   = (u16*)(ws + ((size_t)106 << 20));
    u16*   wvb   = (u16*)(ws + ((size_t)108 << 20));
    u16*   w1b   = (u16*)(ws + ((size_t)96 << 20));             // post-pv
    u16*   w2b   = (u16*)(ws + ((size_t)104 << 20));

    dim3 blk(256);
    const u32 M4 = 4u << 20, M1 = 1u << 20;

    // fp32 -> bf16 staging (x + qkv weights)
    cvt_f32_bf16<<<dim3(M4 / 1024), blk, 0, stream>>>(x,  xb,  M4);
    cvt_f32_bf16<<<dim3(M1 / 1024), blk, 0, stream>>>(wq, wqb, M1);
    cvt_f32_bf16<<<dim3(M1 / 1024), blk, 0, stream>>>(wk, wkb, M1);
    cvt_f32_bf16<<<dim3(M1 / 1024), blk, 0, stream>>>(wv, wvb, M1);

    // QKV projections (MFMA): Y = X @ W^T, 4096x1024x1024
    mfma_gemm<0,0,0><<<dim3(8, 32), blk, 0, stream>>>(xb, wqb, nullptr, Yq, 4096, 1024, 1024);
    mfma_gemm<0,0,0><<<dim3(8, 32), blk, 0, stream>>>(xb, wkb, nullptr, Yk, 4096, 1024, 1024);
    mfma_gemm<0,0,0><<<dim3(8, 32), blk, 0, stream>>>(xb, wvb, nullptr, Yv, 4096, 1024, 1024);

    // scores + rel-pos skew (overwrites xb/wqb/... region: they are dead now)
    qk_skew<<<dim3(16, 16, 64), blk, 0, stream>>>(Yq, Yk, relw, sc);
    softmax_b<<<dim3(32768), blk, 0, stream>>>(sc);
    pv_gemm<<<dim3(16, 64), blk, 0, stream>>>(sc, Yv, O);

    // h1 = LN(x + attn_out)
    add_ln<1,0><<<dim3(4096), blk, 0, stream>>>(x, O, g1, be1, h1);

    // FFN weights -> bf16 (scores region is dead after pv_gemm)
    cvt_f32_bf16<<<dim3(M4 / 1024), blk, 0, stream>>>(w1, w1b, M4);
    cvt_f32_bf16<<<dim3(M4 / 1024), blk, 0, stream>>>(w2, w2b, M4);

    // FFN (MFMA): relu(h1 @ w1^T + b1) @ w2^T + b2
    mfma_gemm<1,0,1><<<dim3(32, 32), blk, 0, stream>>>(h1, w1b, b1, ffn1, 4096, 4096, 1024);
    mfma_gemm<0,1,1><<<dim3(8, 32), blk, 0, stream>>>(ffn1, w2b, b2, ffn2, 4096, 1024, 4096);

    // out = LN(h1 + ffn) -> f32
    add_ln<0,1><<<dim3(4096), blk, 0, stream>>>(h1, ffn2, g2, be2, (float*)d_out);
}

// Round 9
// 661.676 us; speedup vs baseline: 3.0426x; 1.2670x over previous
//
#include <hip/hip_runtime.h>

// ---------------------------------------------------------------------------
// EncoderLayer: S=1024, B=4, D=1024, H=16, dh=64, DFF=4096. fp32 I/O.
// R8: qk_skew -> MFMA. scores tile = QK^T/8 + gather(E), E = Qtile @ RwinT,
// Rwin from pre-transposed relwT[bh][u][d] (bf16, lives in O region until
// pv_gemm). Index: skew[s,t] = emd[s, t-s+1023]*[t<=s]; per tile
// E[siw][j] = emd[s0+siw][u0+j], u0 = t0-s0+960, gather j* = 63 + tj - siw.
//
// Workspace map (224 MB):
//  [0,16M)    O f32  (first 8MB doubles as relwT bf16 until pv_gemm)
//  [16M,24M) Yq bf16  [24M,32M) Yk  [32M,40M) Yv
//  [40M,48M)  h1 bf16  [48M,80M) ffn1 bf16  [80M,96M) ffn2 f32
//  [96M,224M) scores bf16 (softmaxed in place)
//    overlap (pre-qk):  xb@96M(8MB) wqb@104M wkb@106M wvb@108M
//    overlap (post-pv): w1b@96M(8MB) w2b@104M(8MB)
// ---------------------------------------------------------------------------

typedef unsigned short u16;
typedef unsigned int u32;
typedef __attribute__((ext_vector_type(4))) float f32x4;
typedef __attribute__((ext_vector_type(8))) short bf16x8;

__device__ __forceinline__ float bf2f(u16 u) { return __uint_as_float(((u32)u) << 16); }
__device__ __forceinline__ u16 f2bf(float f) {
    u32 u = __float_as_uint(f);
    u += 0x7fffu + ((u >> 16) & 1u);   // RNE
    return (u16)(u >> 16);
}
__device__ __forceinline__ void unpack8(uint4 v, float* f) {
    f[0] = __uint_as_float(v.x << 16); f[1] = __uint_as_float(v.x & 0xffff0000u);
    f[2] = __uint_as_float(v.y << 16); f[3] = __uint_as_float(v.y & 0xffff0000u);
    f[4] = __uint_as_float(v.z << 16); f[5] = __uint_as_float(v.z & 0xffff0000u);
    f[6] = __uint_as_float(v.w << 16); f[7] = __uint_as_float(v.w & 0xffff0000u);
}
template<int DT>
__device__ __forceinline__ float load1(const void* P, size_t idx) {
    return (DT == 0) ? bf2f(((const u16*)P)[idx]) : ((const float*)P)[idx];
}

__global__ __launch_bounds__(256) void sentinel_ws(float* out, u32 n)
{
    for (u32 i = blockIdx.x * 256 + threadIdx.x; i < n; i += gridDim.x * 256) out[i] = 31000.0f;
}

// ---------------- fp32 -> bf16 bulk convert (n mult of 4) ------------------
__global__ __launch_bounds__(256) void cvt_f32_bf16(const float* __restrict__ s,
                                                    u16* __restrict__ d, u32 n)
{
    u32 i = (blockIdx.x * 256 + threadIdx.x) * 4;
    if (i >= n) return;
    float4 v = *(const float4*)(s + i);
    uint2 pk;
    pk.x = (u32)f2bf(v.x) | ((u32)f2bf(v.y) << 16);
    pk.y = (u32)f2bf(v.z) | ((u32)f2bf(v.w) << 16);
    *(uint2*)(d + i) = pk;
}

// ------- relwT[bh][u][d] (bf16) = relw[bh][d][u] (fp32) --------------------
// grid (16, 64): x = u-tile (64), y = bh. 64x64 transpose via LDS.
__global__ __launch_bounds__(256) void relw_tr(const float* __restrict__ relw,
                                               u16* __restrict__ relwT)
{
    __shared__ __align__(16) float T[64][68];   // 68-pad: 272B rows, 16B-aligned
    const int tid = threadIdx.x;
    const int bh = blockIdx.y;
    const int u0 = blockIdx.x << 6;
    {
        const int d = tid >> 2, uq = (tid & 3) << 4;
        const float* rp = relw + (size_t)bh * 65536 + (size_t)d * 1024 + u0 + uq;
#pragma unroll
        for (int i = 0; i < 4; i++)
            *(float4*)&T[d][uq + i * 4] = *(const float4*)(rp + i * 4);
    }
    __syncthreads();
    {
        const int u = tid >> 2, dq = (tid & 3) << 4;
        u32 pk[8];
#pragma unroll
        for (int p = 0; p < 8; p++) {
            float a = T[dq + p * 2][u], b = T[dq + p * 2 + 1][u];
            pk[p] = (u32)f2bf(a) | ((u32)f2bf(b) << 16);
        }
        u16* op = relwT + ((size_t)(bh * 1024 + u0 + u) << 6) + dq;
        *(uint4*)op = *(uint4*)&pk[0];
        *(uint4*)(op + 8) = *(uint4*)&pk[4];
    }
}

// --------------- MFMA GEMM: C[M,N] = act(A[M,K] @ B[N,K]^T + bias) ---------
template<int RELU, int OUT_F32, int HAS_BIAS>
__global__ __launch_bounds__(256) void mfma_gemm(
    const u16* __restrict__ A, const u16* __restrict__ B,
    const float* __restrict__ bias, void* __restrict__ Cout,
    int M, int N, int K)
{
    __shared__ __align__(16) u16 As[4096];
    __shared__ __align__(16) u16 Bs[4096];
    const int tid = threadIdx.x;
    const int wave = tid >> 6, lane = tid & 63;
    const int quad = lane >> 4, l16 = lane & 15;
    const int m0 = blockIdx.y << 7, n0 = blockIdx.x << 7;
    const int wm = (wave >> 1) << 6, wn = (wave & 1) << 6;

    const int r0 = tid >> 2;
    const int csw = ((tid & 3) ^ ((r0 >> 1) & 3)) << 3;
    const u16* Ag0 = A + (size_t)(m0 + r0) * K + csw;
    const u16* Ag1 = A + (size_t)(m0 + r0 + 64) * K + csw;
    const u16* Bg0 = B + (size_t)(n0 + r0) * K + csw;
    const u16* Bg1 = B + (size_t)(n0 + r0 + 64) * K + csw;

    f32x4 acc[4][4];
#pragma unroll
    for (int i = 0; i < 4; i++)
#pragma unroll
        for (int j = 0; j < 4; j++) acc[i][j] = (f32x4){0.f, 0.f, 0.f, 0.f};

    const int pb = ((quad ^ ((l16 >> 1) & 3)) << 3);

    for (int k0 = 0; k0 < K; k0 += 32) {
        uint4 a0 = *(const uint4*)(Ag0 + k0);
        uint4 a1 = *(const uint4*)(Ag1 + k0);
        uint4 b0 = *(const uint4*)(Bg0 + k0);
        uint4 b1 = *(const uint4*)(Bg1 + k0);
        __syncthreads();
        *(uint4*)(As + tid * 8)        = a0;
        *(uint4*)(As + 2048 + tid * 8) = a1;
        *(uint4*)(Bs + tid * 8)        = b0;
        *(uint4*)(Bs + 2048 + tid * 8) = b1;
        __syncthreads();

        bf16x8 af[4], bfr[4];
#pragma unroll
        for (int mi = 0; mi < 4; mi++)
            af[mi] = *(const bf16x8*)(As + ((wm + mi * 16 + l16) << 5) + pb);
#pragma unroll
        for (int ni = 0; ni < 4; ni++)
            bfr[ni] = *(const bf16x8*)(Bs + ((wn + ni * 16 + l16) << 5) + pb);
#pragma unroll
        for (int mi = 0; mi < 4; mi++)
#pragma unroll
            for (int ni = 0; ni < 4; ni++)
                acc[mi][ni] = __builtin_amdgcn_mfma_f32_16x16x32_bf16(
                    af[mi], bfr[ni], acc[mi][ni], 0, 0, 0);
    }

    float bb[4];
#pragma unroll
    for (int ni = 0; ni < 4; ni++)
        bb[ni] = HAS_BIAS ? bias[n0 + wn + ni * 16 + l16] : 0.f;

#pragma unroll
    for (int mi = 0; mi < 4; mi++) {
#pragma unroll
        for (int ni = 0; ni < 4; ni++) {
            const int col = n0 + wn + ni * 16 + l16;
#pragma unroll
            for (int r = 0; r < 4; r++) {
                const int row = m0 + wm + mi * 16 + quad * 4 + r;
                float v = acc[mi][ni][r] + bb[ni];
                if (RELU) v = fmaxf(v, 0.f);
                if (OUT_F32) ((float*)Cout)[(size_t)row * N + col] = v;
                else ((u16*)Cout)[(size_t)row * N + col] = f2bf(v);
            }
        }
    }
}

// ------- scores tile via MFMA: QK^T/8 + skew-gather from E = Q @ RwinT -----
// 64x64 (s,t) tile, 4 waves; wave w owns s-strip [16w,16w+16).
// LDS (u16 units): Qs[64][72]@0, Ks[64][72]@4608, Rw[128][72]@9216,
// Eb[64][136]@18432 (per-wave-private strips). Ssh overlays Qs (stride 72).
__global__ __launch_bounds__(256) void qk_skew_mfma(
    const u16* __restrict__ Yq, const u16* __restrict__ Yk,
    const u16* __restrict__ relwT, u16* __restrict__ scores)
{
    __shared__ __align__(16) u16 lds[27136];
    u16* Qs = lds;
    u16* Ks = lds + 4608;
    u16* Rw = lds + 9216;
    u16* Eb = lds + 18432;
    u16* Ssh = lds;                      // overlay Qs (wave-private strips)

    const int tid = threadIdx.x;
    const int w = tid >> 6, lane = tid & 63;
    const int quad = lane >> 4, l16 = lane & 15;
    const int bh = blockIdx.z, b = bh >> 4, h = bh & 15;
    const int s0 = blockIdx.y << 6, t0 = blockIdx.x << 6;
    const int skew_mode = (t0 < s0) ? 2 : ((t0 == s0) ? 1 : 0);
    const int u0 = t0 - s0 + 960;

    // ---- stage Q, K (64 rows x 64 d), and Rwin (128 rows x 64 d) ----
#pragma unroll
    for (int it = 0; it < 2; it++) {
        const int task = it * 256 + tid;
        const int r = task >> 3, c = (task & 7) << 3;
        *(uint4*)(Qs + r * 72 + c) =
            *(const uint4*)(Yq + ((size_t)(b * 1024 + s0 + r) << 10) + h * 64 + c);
        *(uint4*)(Ks + r * 72 + c) =
            *(const uint4*)(Yk + ((size_t)(b * 1024 + t0 + r) << 10) + h * 64 + c);
    }
    if (skew_mode) {
#pragma unroll
        for (int it = 0; it < 4; it++) {
            const int task = it * 256 + tid;
            const int j = task >> 3, c = (task & 7) << 3;
            const int u = u0 + j;
            uint4 v = {0, 0, 0, 0};
            if (u < 1024)
                v = *(const uint4*)(relwT + ((size_t)(bh * 1024 + u) << 6) + c);
            *(uint4*)(Rw + j * 72 + c) = v;
        }
    }
    __syncthreads();

    // ---- A fragments (own s-strip), K-dim = 64 -> 2 steps ----
    bf16x8 af[2];
    af[0] = *(const bf16x8*)(Qs + (w * 16 + l16) * 72 + quad * 8);
    af[1] = *(const bf16x8*)(Qs + (w * 16 + l16) * 72 + 32 + quad * 8);

    // ---- QK^T: 4 n-tiles ----
    f32x4 aqk[4];
#pragma unroll
    for (int i = 0; i < 4; i++) aqk[i] = (f32x4){0.f, 0.f, 0.f, 0.f};
#pragma unroll
    for (int kk = 0; kk < 2; kk++) {
#pragma unroll
        for (int nj = 0; nj < 4; nj++) {
            bf16x8 bq = *(const bf16x8*)(Ks + (nj * 16 + l16) * 72 + kk * 32 + quad * 8);
            aqk[nj] = __builtin_amdgcn_mfma_f32_16x16x32_bf16(af[kk], bq, aqk[nj], 0, 0, 0);
        }
    }

    // ---- E = Q @ RwinT: 8 j-tiles; write own strip to Eb, no barrier ----
    if (skew_mode) {
        f32x4 ae[8];
#pragma unroll
        for (int i = 0; i < 8; i++) ae[i] = (f32x4){0.f, 0.f, 0.f, 0.f};
#pragma unroll
        for (int kk = 0; kk < 2; kk++) {
#pragma unroll
            for (int nj = 0; nj < 8; nj++) {
                bf16x8 br = *(const bf16x8*)(Rw + (nj * 16 + l16) * 72 + kk * 32 + quad * 8);
                ae[nj] = __builtin_amdgcn_mfma_f32_16x16x32_bf16(af[kk], br, ae[nj], 0, 0, 0);
            }
        }
#pragma unroll
        for (int nj = 0; nj < 8; nj++)
#pragma unroll
            for (int r = 0; r < 4; r++)
                Eb[(w * 16 + quad * 4 + r) * 136 + nj * 16 + l16] = f2bf(ae[nj][r]);
    }

    // ---- combine + gather; write own Ssh strip (overlays own Qs strip) ----
#pragma unroll
    for (int nj = 0; nj < 4; nj++) {
#pragma unroll
        for (int r = 0; r < 4; r++) {
            const int siw = w * 16 + quad * 4 + r;
            const int tj = nj * 16 + l16;
            float e = 0.f;
            if (skew_mode == 2 || (skew_mode == 1 && tj <= siw))
                e = bf2f(Eb[siw * 135 + 63 + tj]);   // siw*136 + 63 + tj - siw
            Ssh[siw * 72 + tj] = f2bf(aqk[nj][r] * 0.125f + e);
        }
    }
    __syncthreads();

    // ---- coalesced store: 64 rows x 64 cols bf16 ----
    {
        const int row = tid >> 2, cc = (tid & 3) << 4;
        uint4 v0 = *(const uint4*)(Ssh + row * 72 + cc);
        uint4 v1 = *(const uint4*)(Ssh + row * 72 + cc + 8);
        u16* op = scores + (((size_t)bh * 1024 + s0 + row) << 10) + t0 + cc;
        *(uint4*)op = v0;
        *(uint4*)(op + 8) = v1;
    }
}

// ---------------- softmax over batch dim (4 values), in place --------------
__global__ __launch_bounds__(256) void softmax_b(u16* __restrict__ sc)
{
    const size_t e = ((size_t)blockIdx.x * 256 + threadIdx.x) * 2;
    const size_t bs = (size_t)16 * 1024 * 1024;
    float x[4][2];
#pragma unroll
    for (int b = 0; b < 4; b++) {
        u32 v = *(const u32*)(sc + b * bs + e);
        x[b][0] = __uint_as_float(v << 16);
        x[b][1] = __uint_as_float(v & 0xffff0000u);
    }
#pragma unroll
    for (int sl = 0; sl < 2; sl++) {
        float m = fmaxf(fmaxf(x[0][sl], x[1][sl]), fmaxf(x[2][sl], x[3][sl]));
        float ex[4], s = 0.f;
#pragma unroll
        for (int b = 0; b < 4; b++) { ex[b] = __expf(x[b][sl] - m); s += ex[b]; }
        float inv = 1.f / s;
#pragma unroll
        for (int b = 0; b < 4; b++) x[b][sl] = ex[b] * inv;
    }
#pragma unroll
    for (int b = 0; b < 4; b++) {
        u32 v = (u32)f2bf(x[b][0]) | ((u32)f2bf(x[b][1]) << 16);
        *(u32*)(sc + b * bs + e) = v;
    }
}

// ------------- O[b,h,s,d] = sum_t attn[b,h,s,t] * V[b,h,t,d] ---------------
__global__ __launch_bounds__(256) void pv_gemm(
    const u16* __restrict__ attn, const u16* __restrict__ Yv, float* __restrict__ O)
{
    __shared__ __align__(16) float Ps[32][68];
    __shared__ __align__(16) float Vs[32][68];
    const int tid = threadIdx.x;
    const int bh = blockIdx.y, b = bh >> 4, h = bh & 15;
    const int s0 = blockIdx.x << 6;
    const int ty = tid >> 4, tx = tid & 15;
    const int pr = tid >> 2, pq = (tid & 3) << 3;
    const int vr = tid >> 3, vq = (tid & 7) << 3;

    float acc[4][4];
#pragma unroll
    for (int i = 0; i < 4; i++)
#pragma unroll
        for (int j = 0; j < 4; j++) acc[i][j] = 0.f;

    for (int t0 = 0; t0 < 1024; t0 += 32) {
        uint4 pa = *(const uint4*)(attn + ((size_t)bh * 1024 + s0 + pr) * 1024 + t0 + pq);
        uint4 va = *(const uint4*)(Yv + (size_t)(b * 1024 + t0 + vr) * 1024 + h * 64 + vq);
        float pf[8], vf[8];
        unpack8(pa, pf); unpack8(va, vf);
        __syncthreads();
#pragma unroll
        for (int i = 0; i < 8; i++) Ps[pq + i][pr] = pf[i];
        float4 w0, w1;
        w0.x = vf[0]; w0.y = vf[1]; w0.z = vf[2]; w0.w = vf[3];
        w1.x = vf[4]; w1.y = vf[5]; w1.z = vf[6]; w1.w = vf[7];
        *(float4*)&Vs[vr][vq] = w0;
        *(float4*)&Vs[vr][vq + 4] = w1;
        __syncthreads();
#pragma unroll
        for (int k = 0; k < 32; k++) {
            float a[4], v[4];
            *(float4*)a = *(const float4*)&Ps[k][ty * 4];
            *(float4*)v = *(const float4*)&Vs[k][tx * 4];
#pragma unroll
            for (int si = 0; si < 4; si++)
#pragma unroll
                for (int di = 0; di < 4; di++) acc[si][di] = fmaf(a[si], v[di], acc[si][di]);
        }
    }
#pragma unroll
    for (int si = 0; si < 4; si++) {
        float4 w;
        w.x = acc[si][0]; w.y = acc[si][1]; w.z = acc[si][2]; w.w = acc[si][3];
        *(float4*)(O + ((size_t)bh * 1024 + s0 + ty * 4 + si) * 64 + tx * 4) = w;
    }
}

// ------------- out = LN(A + f32 B) * g + beta ------------------------------
template<int DTA, int OUT_F32>
__global__ __launch_bounds__(256) void add_ln(
    const void* __restrict__ A, const float* __restrict__ Bf,
    const float* __restrict__ g, const float* __restrict__ beta,
    void* __restrict__ out)
{
    const int row = blockIdx.x;
    const int tid = threadIdx.x;
    const size_t base = (size_t)row * 1024;
    float v[4], s1 = 0.f, s2 = 0.f;
#pragma unroll
    for (int k = 0; k < 4; k++) {
        const int c = k * 256 + tid;
        float t = load1<DTA>(A, base + c) + Bf[base + c];
        v[k] = t; s1 += t; s2 += t * t;
    }
#pragma unroll
    for (int m = 1; m < 64; m <<= 1) {
        s1 += __shfl_xor(s1, m, 64);
        s2 += __shfl_xor(s2, m, 64);
    }
    __shared__ float red[8];
    if ((tid & 63) == 0) { red[(tid >> 6) * 2] = s1; red[(tid >> 6) * 2 + 1] = s2; }
    __syncthreads();
    s1 = red[0] + red[2] + red[4] + red[6];
    s2 = red[1] + red[3] + red[5] + red[7];
    const float mean = s1 * (1.f / 1024.f);
    const float var = s2 * (1.f / 1024.f) - mean * mean;
    const float rstd = rsqrtf(var + 1e-5f);
#pragma unroll
    for (int k = 0; k < 4; k++) {
        const int c = k * 256 + tid;
        float o = (v[k] - mean) * rstd * g[c] + beta[c];
        if (OUT_F32) ((float*)out)[base + c] = o;
        else ((u16*)out)[base + c] = f2bf(o);
    }
}

// ---------------------------------------------------------------------------
extern "C" void kernel_launch(void* const* d_in, const int* in_sizes, int n_in,
                              void* d_out, int out_size, void* d_ws, size_t ws_size,
                              hipStream_t stream)
{
    const float* x    = (const float*)d_in[0];
    const float* wq   = (const float*)d_in[1];
    const float* wk   = (const float*)d_in[2];
    const float* wv   = (const float*)d_in[3];
    const float* relw = (const float*)d_in[4];
    const float* g1   = (const float*)d_in[5];
    const float* be1  = (const float*)d_in[6];
    const float* g2   = (const float*)d_in[7];
    const float* be2  = (const float*)d_in[8];
    const float* w1   = (const float*)d_in[9];
    const float* b1   = (const float*)d_in[10];
    const float* w2   = (const float*)d_in[11];
    const float* b2   = (const float*)d_in[12];

    const size_t NEEDED = ((size_t)224 << 20);
    if (ws_size < NEEDED) {
        sentinel_ws<<<dim3(1024), dim3(256), 0, stream>>>((float*)d_out, (u32)out_size);
        return;
    }

    char* ws = (char*)d_ws;
    float* O     = (float*)(ws);
    u16*   relwT = (u16*)(ws);                                  // dies before pv_gemm
    u16*   Yq    = (u16*)(ws + ((size_t)16 << 20));
    u16*   Yk    = (u16*)(ws + ((size_t)24 << 20));
    u16*   Yv    = (u16*)(ws + ((size_t)32 << 20));
    u16*   h1    = (u16*)(ws + ((size_t)40 << 20));
    u16*   ffn1  = (u16*)(ws + ((size_t)48 << 20));
    float* ffn2  = (float*)(ws + ((size_t)80 << 20));
    u16*   sc    = (u16*)(ws + ((size_t)96 << 20));
    u16*   xb    = (u16*)(ws + ((size_t)96 << 20));             // pre-qk
    u16*   wqb   = (u16*)(ws + ((size_t)104 << 20));
    u16*   wkb   = (u16*)(ws + ((size_t)106 << 20));
    u16*   wvb   = (u16*)(ws + ((size_t)108 << 20));
    u16*   w1b   = (u16*)(ws + ((size_t)96 << 20));             // post-pv
    u16*   w2b   = (u16*)(ws + ((size_t)104 << 20));

    dim3 blk(256);
    const u32 M4 = 4u << 20, M1 = 1u << 20;

    // fp32 -> bf16 staging (x + qkv weights) + relw transpose
    cvt_f32_bf16<<<dim3(M4 / 1024), blk, 0, stream>>>(x,  xb,  M4);
    cvt_f32_bf16<<<dim3(M1 / 1024), blk, 0, stream>>>(wq, wqb, M1);
    cvt_f32_bf16<<<dim3(M1 / 1024), blk, 0, stream>>>(wk, wkb, M1);
    cvt_f32_bf16<<<dim3(M1 / 1024), blk, 0, stream>>>(wv, wvb, M1);
    relw_tr<<<dim3(16, 64), blk, 0, stream>>>(relw, relwT);

    // QKV projections (MFMA)
    mfma_gemm<0,0,0><<<dim3(8, 32), blk, 0, stream>>>(xb, wqb, nullptr, Yq, 4096, 1024, 1024);
    mfma_gemm<0,0,0><<<dim3(8, 32), blk, 0, stream>>>(xb, wkb, nullptr, Yk, 4096, 1024, 1024);
    mfma_gemm<0,0,0><<<dim3(8, 32), blk, 0, stream>>>(xb, wvb, nullptr, Yv, 4096, 1024, 1024);

    // scores + rel-pos skew (MFMA)
    qk_skew_mfma<<<dim3(16, 16, 64), blk, 0, stream>>>(Yq, Yk, relwT, sc);
    softmax_b<<<dim3(32768), blk, 0, stream>>>(sc);
    pv_gemm<<<dim3(16, 64), blk, 0, stream>>>(sc, Yv, O);

    // h1 = LN(x + attn_out)
    add_ln<1,0><<<dim3(4096), blk, 0, stream>>>(x, O, g1, be1, h1);

    // FFN weights -> bf16 (scores region dead after pv_gemm)
    cvt_f32_bf16<<<dim3(M4 / 1024), blk, 0, stream>>>(w1, w1b, M4);
    cvt_f32_bf16<<<dim3(M4 / 1024), blk, 0, stream>>>(w2, w2b, M4);

    // FFN (MFMA)
    mfma_gemm<1,0,1><<<dim3(32, 32), blk, 0, stream>>>(h1, w1b, b1, ffn1, 4096, 4096, 1024);
    mfma_gemm<0,1,1><<<dim3(8, 32), blk, 0, stream>>>(ffn1, w2b, b2, ffn2, 4096, 1024, 4096);

    // out = LN(h1 + ffn) -> f32
    add_ln<0,1><<<dim3(4096), blk, 0, stream>>>(h1, ffn2, g2, be2, (float*)d_out);
}

// Round 10
// 545.137 us; speedup vs baseline: 3.6930x; 1.2138x over previous
//
#include <hip/hip_runtime.h>

// ---------------------------------------------------------------------------
// EncoderLayer: S=1024, B=4, D=1024, H=16, dh=64, DFF=4096. fp32 I/O.
// R9: pv -> MFMA (via pre-transposed YvT[bh][d][t] in ffn2 region) and
// software-prefetch in mfma_gemm (overlap next-tile global loads with MFMA).
//
// Workspace map (224 MB):
//  [0,16M)    O f32  (first 8MB doubles as relwT bf16 until pv)
//  [16M,24M) Yq bf16  [24M,32M) Yk  [32M,40M) Yv
//  [40M,48M)  h1 bf16  [48M,80M) ffn1 bf16
//  [80M,96M)  ffn2 f32 (first 8MB doubles as YvT bf16 until ffn2 GEMM)
//  [96M,224M) scores bf16 (softmaxed in place)
//    overlap (pre-qk):  xb@96M(8MB) wqb@104M wkb@106M wvb@108M
//    overlap (post-pv): w1b@96M(8MB) w2b@104M(8MB)
// ---------------------------------------------------------------------------

typedef unsigned short u16;
typedef unsigned int u32;
typedef __attribute__((ext_vector_type(4))) float f32x4;
typedef __attribute__((ext_vector_type(8))) short bf16x8;

__device__ __forceinline__ float bf2f(u16 u) { return __uint_as_float(((u32)u) << 16); }
__device__ __forceinline__ u16 f2bf(float f) {
    u32 u = __float_as_uint(f);
    u += 0x7fffu + ((u >> 16) & 1u);   // RNE
    return (u16)(u >> 16);
}
template<int DT>
__device__ __forceinline__ float load1(const void* P, size_t idx) {
    return (DT == 0) ? bf2f(((const u16*)P)[idx]) : ((const float*)P)[idx];
}

__global__ __launch_bounds__(256) void sentinel_ws(float* out, u32 n)
{
    for (u32 i = blockIdx.x * 256 + threadIdx.x; i < n; i += gridDim.x * 256) out[i] = 31000.0f;
}

// ---------------- fp32 -> bf16 bulk convert (n mult of 4) ------------------
__global__ __launch_bounds__(256) void cvt_f32_bf16(const float* __restrict__ s,
                                                    u16* __restrict__ d, u32 n)
{
    u32 i = (blockIdx.x * 256 + threadIdx.x) * 4;
    if (i >= n) return;
    float4 v = *(const float4*)(s + i);
    uint2 pk;
    pk.x = (u32)f2bf(v.x) | ((u32)f2bf(v.y) << 16);
    pk.y = (u32)f2bf(v.z) | ((u32)f2bf(v.w) << 16);
    *(uint2*)(d + i) = pk;
}

// ------- relwT[bh][u][d] (bf16) = relw[bh][d][u] (fp32) --------------------
__global__ __launch_bounds__(256) void relw_tr(const float* __restrict__ relw,
                                               u16* __restrict__ relwT)
{
    __shared__ __align__(16) float T[64][68];
    const int tid = threadIdx.x;
    const int bh = blockIdx.y;
    const int u0 = blockIdx.x << 6;
    {
        const int d = tid >> 2, uq = (tid & 3) << 4;
        const float* rp = relw + (size_t)bh * 65536 + (size_t)d * 1024 + u0 + uq;
#pragma unroll
        for (int i = 0; i < 4; i++)
            *(float4*)&T[d][uq + i * 4] = *(const float4*)(rp + i * 4);
    }
    __syncthreads();
    {
        const int u = tid >> 2, dq = (tid & 3) << 4;
        u32 pk[8];
#pragma unroll
        for (int p = 0; p < 8; p++) {
            float a = T[dq + p * 2][u], b = T[dq + p * 2 + 1][u];
            pk[p] = (u32)f2bf(a) | ((u32)f2bf(b) << 16);
        }
        u16* op = relwT + ((size_t)(bh * 1024 + u0 + u) << 6) + dq;
        *(uint4*)op = *(uint4*)&pk[0];
        *(uint4*)(op + 8) = *(uint4*)&pk[4];
    }
}

// ------- YvT[bh][d][t] (bf16) = Yv[(b*1024+t)*1024 + h*64+d] ---------------
__global__ __launch_bounds__(256) void yv_tr(const u16* __restrict__ Yv,
                                             u16* __restrict__ YvT)
{
    __shared__ __align__(16) u16 T[64][72];
    const int tid = threadIdx.x;
    const int bh = blockIdx.y, b = bh >> 4, h = bh & 15;
    const int t0 = blockIdx.x << 6;
    {
        const int r = tid >> 2, cq = (tid & 3) << 4;
        const u16* p = Yv + ((size_t)(b * 1024 + t0 + r) << 10) + h * 64 + cq;
        *(uint4*)&T[r][cq] = *(const uint4*)p;
        *(uint4*)&T[r][cq + 8] = *(const uint4*)(p + 8);
    }
    __syncthreads();
    {
        const int d = tid >> 2, tq = (tid & 3) << 4;
        u16 vals[16];
#pragma unroll
        for (int p = 0; p < 16; p++) vals[p] = T[tq + p][d];
        u16* op = YvT + (((size_t)bh * 64 + d) << 10) + t0 + tq;
        *(uint4*)op = ((uint4*)vals)[0];
        *(uint4*)(op + 8) = ((uint4*)vals)[1];
    }
}

// --------------- MFMA GEMM: C[M,N] = act(A[M,K] @ B[N,K]^T + bias) ---------
// 128x128 tile, BK=32, 4 waves, 4x4 mfma_f32_16x16x32_bf16 per wave.
// XOR-swizzled LDS (2-way bank aliasing = free) + next-tile register prefetch
// issued right after the publish barrier (overlaps global latency with MFMA).
template<int RELU, int OUT_F32, int HAS_BIAS>
__global__ __launch_bounds__(256) void mfma_gemm(
    const u16* __restrict__ A, const u16* __restrict__ B,
    const float* __restrict__ bias, void* __restrict__ Cout,
    int M, int N, int K)
{
    __shared__ __align__(16) u16 As[4096];
    __shared__ __align__(16) u16 Bs[4096];
    const int tid = threadIdx.x;
    const int wave = tid >> 6, lane = tid & 63;
    const int quad = lane >> 4, l16 = lane & 15;
    const int m0 = blockIdx.y << 7, n0 = blockIdx.x << 7;
    const int wm = (wave >> 1) << 6, wn = (wave & 1) << 6;

    const int r0 = tid >> 2;
    const int csw = ((tid & 3) ^ ((r0 >> 1) & 3)) << 3;
    const u16* Ag0 = A + (size_t)(m0 + r0) * K + csw;
    const u16* Ag1 = A + (size_t)(m0 + r0 + 64) * K + csw;
    const u16* Bg0 = B + (size_t)(n0 + r0) * K + csw;
    const u16* Bg1 = B + (size_t)(n0 + r0 + 64) * K + csw;

    f32x4 acc[4][4];
#pragma unroll
    for (int i = 0; i < 4; i++)
#pragma unroll
        for (int j = 0; j < 4; j++) acc[i][j] = (f32x4){0.f, 0.f, 0.f, 0.f};

    const int pb = ((quad ^ ((l16 >> 1) & 3)) << 3);

    uint4 a0 = *(const uint4*)(Ag0);
    uint4 a1 = *(const uint4*)(Ag1);
    uint4 b0 = *(const uint4*)(Bg0);
    uint4 b1 = *(const uint4*)(Bg1);

    for (int k0 = 0; k0 < K; k0 += 32) {
        __syncthreads();
        *(uint4*)(As + tid * 8)        = a0;
        *(uint4*)(As + 2048 + tid * 8) = a1;
        *(uint4*)(Bs + tid * 8)        = b0;
        *(uint4*)(Bs + 2048 + tid * 8) = b1;
        __syncthreads();

        if (k0 + 32 < K) {                  // prefetch next tile
            a0 = *(const uint4*)(Ag0 + k0 + 32);
            a1 = *(const uint4*)(Ag1 + k0 + 32);
            b0 = *(const uint4*)(Bg0 + k0 + 32);
            b1 = *(const uint4*)(Bg1 + k0 + 32);
        }

        bf16x8 af[4], bfr[4];
#pragma unroll
        for (int mi = 0; mi < 4; mi++)
            af[mi] = *(const bf16x8*)(As + ((wm + mi * 16 + l16) << 5) + pb);
#pragma unroll
        for (int ni = 0; ni < 4; ni++)
            bfr[ni] = *(const bf16x8*)(Bs + ((wn + ni * 16 + l16) << 5) + pb);
#pragma unroll
        for (int mi = 0; mi < 4; mi++)
#pragma unroll
            for (int ni = 0; ni < 4; ni++)
                acc[mi][ni] = __builtin_amdgcn_mfma_f32_16x16x32_bf16(
                    af[mi], bfr[ni], acc[mi][ni], 0, 0, 0);
    }

    float bb[4];
#pragma unroll
    for (int ni = 0; ni < 4; ni++)
        bb[ni] = HAS_BIAS ? bias[n0 + wn + ni * 16 + l16] : 0.f;

#pragma unroll
    for (int mi = 0; mi < 4; mi++) {
#pragma unroll
        for (int ni = 0; ni < 4; ni++) {
            const int col = n0 + wn + ni * 16 + l16;
#pragma unroll
            for (int r = 0; r < 4; r++) {
                const int row = m0 + wm + mi * 16 + quad * 4 + r;
                float v = acc[mi][ni][r] + bb[ni];
                if (RELU) v = fmaxf(v, 0.f);
                if (OUT_F32) ((float*)Cout)[(size_t)row * N + col] = v;
                else ((u16*)Cout)[(size_t)row * N + col] = f2bf(v);
            }
        }
    }
}

// ------- scores tile via MFMA: QK^T/8 + skew-gather from E = Q @ RwinT -----
__global__ __launch_bounds__(256) void qk_skew_mfma(
    const u16* __restrict__ Yq, const u16* __restrict__ Yk,
    const u16* __restrict__ relwT, u16* __restrict__ scores)
{
    __shared__ __align__(16) u16 lds[27136];
    u16* Qs = lds;
    u16* Ks = lds + 4608;
    u16* Rw = lds + 9216;
    u16* Eb = lds + 18432;
    u16* Ssh = lds;

    const int tid = threadIdx.x;
    const int w = tid >> 6, lane = tid & 63;
    const int quad = lane >> 4, l16 = lane & 15;
    const int bh = blockIdx.z, b = bh >> 4, h = bh & 15;
    const int s0 = blockIdx.y << 6, t0 = blockIdx.x << 6;
    const int skew_mode = (t0 < s0) ? 2 : ((t0 == s0) ? 1 : 0);
    const int u0 = t0 - s0 + 960;

#pragma unroll
    for (int it = 0; it < 2; it++) {
        const int task = it * 256 + tid;
        const int r = task >> 3, c = (task & 7) << 3;
        *(uint4*)(Qs + r * 72 + c) =
            *(const uint4*)(Yq + ((size_t)(b * 1024 + s0 + r) << 10) + h * 64 + c);
        *(uint4*)(Ks + r * 72 + c) =
            *(const uint4*)(Yk + ((size_t)(b * 1024 + t0 + r) << 10) + h * 64 + c);
    }
    if (skew_mode) {
#pragma unroll
        for (int it = 0; it < 4; it++) {
            const int task = it * 256 + tid;
            const int j = task >> 3, c = (task & 7) << 3;
            const int u = u0 + j;
            uint4 v = {0, 0, 0, 0};
            if (u < 1024)
                v = *(const uint4*)(relwT + ((size_t)(bh * 1024 + u) << 6) + c);
            *(uint4*)(Rw + j * 72 + c) = v;
        }
    }
    __syncthreads();

    bf16x8 af[2];
    af[0] = *(const bf16x8*)(Qs + (w * 16 + l16) * 72 + quad * 8);
    af[1] = *(const bf16x8*)(Qs + (w * 16 + l16) * 72 + 32 + quad * 8);

    f32x4 aqk[4];
#pragma unroll
    for (int i = 0; i < 4; i++) aqk[i] = (f32x4){0.f, 0.f, 0.f, 0.f};
#pragma unroll
    for (int kk = 0; kk < 2; kk++) {
#pragma unroll
        for (int nj = 0; nj < 4; nj++) {
            bf16x8 bq = *(const bf16x8*)(Ks + (nj * 16 + l16) * 72 + kk * 32 + quad * 8);
            aqk[nj] = __builtin_amdgcn_mfma_f32_16x16x32_bf16(af[kk], bq, aqk[nj], 0, 0, 0);
        }
    }

    if (skew_mode) {
        f32x4 ae[8];
#pragma unroll
        for (int i = 0; i < 8; i++) ae[i] = (f32x4){0.f, 0.f, 0.f, 0.f};
#pragma unroll
        for (int kk = 0; kk < 2; kk++) {
#pragma unroll
            for (int nj = 0; nj < 8; nj++) {
                bf16x8 br = *(const bf16x8*)(Rw + (nj * 16 + l16) * 72 + kk * 32 + quad * 8);
                ae[nj] = __builtin_amdgcn_mfma_f32_16x16x32_bf16(af[kk], br, ae[nj], 0, 0, 0);
            }
        }
#pragma unroll
        for (int nj = 0; nj < 8; nj++)
#pragma unroll
            for (int r = 0; r < 4; r++)
                Eb[(w * 16 + quad * 4 + r) * 136 + nj * 16 + l16] = f2bf(ae[nj][r]);
    }

#pragma unroll
    for (int nj = 0; nj < 4; nj++) {
#pragma unroll
        for (int r = 0; r < 4; r++) {
            const int siw = w * 16 + quad * 4 + r;
            const int tj = nj * 16 + l16;
            float e = 0.f;
            if (skew_mode == 2 || (skew_mode == 1 && tj <= siw))
                e = bf2f(Eb[siw * 135 + 63 + tj]);
            Ssh[siw * 72 + tj] = f2bf(aqk[nj][r] * 0.125f + e);
        }
    }
    __syncthreads();

    {
        const int row = tid >> 2, cc = (tid & 3) << 4;
        uint4 v0 = *(const uint4*)(Ssh + row * 72 + cc);
        uint4 v1 = *(const uint4*)(Ssh + row * 72 + cc + 8);
        u16* op = scores + (((size_t)bh * 1024 + s0 + row) << 10) + t0 + cc;
        *(uint4*)op = v0;
        *(uint4*)(op + 8) = v1;
    }
}

// ---------------- softmax over batch dim (4 values), in place --------------
__global__ __launch_bounds__(256) void softmax_b(u16* __restrict__ sc)
{
    const size_t e = ((size_t)blockIdx.x * 256 + threadIdx.x) * 2;
    const size_t bs = (size_t)16 * 1024 * 1024;
    float x[4][2];
#pragma unroll
    for (int b = 0; b < 4; b++) {
        u32 v = *(const u32*)(sc + b * bs + e);
        x[b][0] = __uint_as_float(v << 16);
        x[b][1] = __uint_as_float(v & 0xffff0000u);
    }
#pragma unroll
    for (int sl = 0; sl < 2; sl++) {
        float m = fmaxf(fmaxf(x[0][sl], x[1][sl]), fmaxf(x[2][sl], x[3][sl]));
        float ex[4], s = 0.f;
#pragma unroll
        for (int b = 0; b < 4; b++) { ex[b] = __expf(x[b][sl] - m); s += ex[b]; }
        float inv = 1.f / s;
#pragma unroll
        for (int b = 0; b < 4; b++) x[b][sl] = ex[b] * inv;
    }
#pragma unroll
    for (int b = 0; b < 4; b++) {
        u32 v = (u32)f2bf(x[b][0]) | ((u32)f2bf(x[b][1]) << 16);
        *(u32*)(sc + b * bs + e) = v;
    }
}

// ------------- O[bh][s][d] = sum_t attn[bh][s][t] * YvT[bh][d][t] (MFMA) ---
// 64x64 output tile per block (grid: 16 s-tiles x 64 bh), 4 waves, K=1024 in
// 16 chunks of 64. Wave w owns s-strip [16w,16w+16): 8 MFMAs/chunk.
__global__ __launch_bounds__(256) void pv_mfma(
    const u16* __restrict__ attn, const u16* __restrict__ YvT,
    float* __restrict__ O)
{
    __shared__ __align__(16) u16 Ps[64 * 72];
    __shared__ __align__(16) u16 Vt[64 * 72];
    const int tid = threadIdx.x;
    const int w = tid >> 6, lane = tid & 63;
    const int quad = lane >> 4, l16 = lane & 15;
    const int bh = blockIdx.y;
    const int s0 = blockIdx.x << 6;

    const int sr0 = tid >> 3, sc0 = (tid & 7) << 3;       // staging row/col (it=0)
    const u16* Pg = attn + ((size_t)(bh * 1024 + s0) << 10);
    const u16* Vg = YvT + ((size_t)bh << 16);

    f32x4 acc[4];
#pragma unroll
    for (int i = 0; i < 4; i++) acc[i] = (f32x4){0.f, 0.f, 0.f, 0.f};

    uint4 p0 = *(const uint4*)(Pg + ((size_t)sr0 << 10) + sc0);
    uint4 p1 = *(const uint4*)(Pg + ((size_t)(sr0 + 32) << 10) + sc0);
    uint4 v0 = *(const uint4*)(Vg + ((size_t)sr0 << 10) + sc0);
    uint4 v1 = *(const uint4*)(Vg + ((size_t)(sr0 + 32) << 10) + sc0);

    for (int t0 = 0; t0 < 1024; t0 += 64) {
        __syncthreads();
        *(uint4*)(Ps + sr0 * 72 + sc0) = p0;
        *(uint4*)(Ps + (sr0 + 32) * 72 + sc0) = p1;
        *(uint4*)(Vt + sr0 * 72 + sc0) = v0;
        *(uint4*)(Vt + (sr0 + 32) * 72 + sc0) = v1;
        __syncthreads();

        if (t0 + 64 < 1024) {             // prefetch next chunk
            p0 = *(const uint4*)(Pg + ((size_t)sr0 << 10) + t0 + 64 + sc0);
            p1 = *(const uint4*)(Pg + ((size_t)(sr0 + 32) << 10) + t0 + 64 + sc0);
            v0 = *(const uint4*)(Vg + ((size_t)sr0 << 10) + t0 + 64 + sc0);
            v1 = *(const uint4*)(Vg + ((size_t)(sr0 + 32) << 10) + t0 + 64 + sc0);
        }

#pragma unroll
        for (int kk = 0; kk < 2; kk++) {
            bf16x8 af = *(const bf16x8*)(Ps + (w * 16 + l16) * 72 + kk * 32 + quad * 8);
#pragma unroll
            for (int nj = 0; nj < 4; nj++) {
                bf16x8 bv = *(const bf16x8*)(Vt + (nj * 16 + l16) * 72 + kk * 32 + quad * 8);
                acc[nj] = __builtin_amdgcn_mfma_f32_16x16x32_bf16(af, bv, acc[nj], 0, 0, 0);
            }
        }
    }

#pragma unroll
    for (int nj = 0; nj < 4; nj++)
#pragma unroll
        for (int r = 0; r < 4; r++) {
            const int row = s0 + w * 16 + quad * 4 + r;
            O[(((size_t)bh << 10) + row << 6) + nj * 16 + l16] = acc[nj][r];
        }
}

// ------------- out = LN(A + f32 B) * g + beta ------------------------------
template<int DTA, int OUT_F32>
__global__ __launch_bounds__(256) void add_ln(
    const void* __restrict__ A, const float* __restrict__ Bf,
    const float* __restrict__ g, const float* __restrict__ beta,
    void* __restrict__ out)
{
    const int row = blockIdx.x;
    const int tid = threadIdx.x;
    const size_t base = (size_t)row * 1024;
    float v[4], s1 = 0.f, s2 = 0.f;
#pragma unroll
    for (int k = 0; k < 4; k++) {
        const int c = k * 256 + tid;
        float t = load1<DTA>(A, base + c) + Bf[base + c];
        v[k] = t; s1 += t; s2 += t * t;
    }
#pragma unroll
    for (int m = 1; m < 64; m <<= 1) {
        s1 += __shfl_xor(s1, m, 64);
        s2 += __shfl_xor(s2, m, 64);
    }
    __shared__ float red[8];
    if ((tid & 63) == 0) { red[(tid >> 6) * 2] = s1; red[(tid >> 6) * 2 + 1] = s2; }
    __syncthreads();
    s1 = red[0] + red[2] + red[4] + red[6];
    s2 = red[1] + red[3] + red[5] + red[7];
    const float mean = s1 * (1.f / 1024.f);
    const float var = s2 * (1.f / 1024.f) - mean * mean;
    const float rstd = rsqrtf(var + 1e-5f);
#pragma unroll
    for (int k = 0; k < 4; k++) {
        const int c = k * 256 + tid;
        float o = (v[k] - mean) * rstd * g[c] + beta[c];
        if (OUT_F32) ((float*)out)[base + c] = o;
        else ((u16*)out)[base + c] = f2bf(o);
    }
}

// ---------------------------------------------------------------------------
extern "C" void kernel_launch(void* const* d_in, const int* in_sizes, int n_in,
                              void* d_out, int out_size, void* d_ws, size_t ws_size,
                              hipStream_t stream)
{
    const float* x    = (const float*)d_in[0];
    const float* wq   = (const float*)d_in[1];
    const float* wk   = (const float*)d_in[2];
    const float* wv   = (const float*)d_in[3];
    const float* relw = (const float*)d_in[4];
    const float* g1   = (const float*)d_in[5];
    const float* be1  = (const float*)d_in[6];
    const float* g2   = (const float*)d_in[7];
    const float* be2  = (const float*)d_in[8];
    const float* w1   = (const float*)d_in[9];
    const float* b1   = (const float*)d_in[10];
    const float* w2   = (const float*)d_in[11];
    const float* b2   = (const float*)d_in[12];

    const size_t NEEDED = ((size_t)224 << 20);
    if (ws_size < NEEDED) {
        sentinel_ws<<<dim3(1024), dim3(256), 0, stream>>>((float*)d_out, (u32)out_size);
        return;
    }

    char* ws = (char*)d_ws;
    float* O     = (float*)(ws);
    u16*   relwT = (u16*)(ws);                                  // dies before pv
    u16*   Yq    = (u16*)(ws + ((size_t)16 << 20));
    u16*   Yk    = (u16*)(ws + ((size_t)24 << 20));
    u16*   Yv    = (u16*)(ws + ((size_t)32 << 20));
    u16*   h1    = (u16*)(ws + ((size_t)40 << 20));
    u16*   ffn1  = (u16*)(ws + ((size_t)48 << 20));
    float* ffn2  = (float*)(ws + ((size_t)80 << 20));
    u16*   YvT   = (u16*)(ws + ((size_t)80 << 20));             // dies before ffn2
    u16*   sc    = (u16*)(ws + ((size_t)96 << 20));
    u16*   xb    = (u16*)(ws + ((size_t)96 << 20));             // pre-qk
    u16*   wqb   = (u16*)(ws + ((size_t)104 << 20));
    u16*   wkb   = (u16*)(ws + ((size_t)106 << 20));
    u16*   wvb   = (u16*)(ws + ((size_t)108 << 20));
    u16*   w1b   = (u16*)(ws + ((size_t)96 << 20));             // post-pv
    u16*   w2b   = (u16*)(ws + ((size_t)104 << 20));

    dim3 blk(256);
    const u32 M4 = 4u << 20, M1 = 1u << 20;

    // fp32 -> bf16 staging + relw transpose
    cvt_f32_bf16<<<dim3(M4 / 1024), blk, 0, stream>>>(x,  xb,  M4);
    cvt_f32_bf16<<<dim3(M1 / 1024), blk, 0, stream>>>(wq, wqb, M1);
    cvt_f32_bf16<<<dim3(M1 / 1024), blk, 0, stream>>>(wk, wkb, M1);
    cvt_f32_bf16<<<dim3(M1 / 1024), blk, 0, stream>>>(wv, wvb, M1);
    relw_tr<<<dim3(16, 64), blk, 0, stream>>>(relw, relwT);

    // QKV projections (MFMA)
    mfma_gemm<0,0,0><<<dim3(8, 32), blk, 0, stream>>>(xb, wqb, nullptr, Yq, 4096, 1024, 1024);
    mfma_gemm<0,0,0><<<dim3(8, 32), blk, 0, stream>>>(xb, wkb, nullptr, Yk, 4096, 1024, 1024);
    mfma_gemm<0,0,0><<<dim3(8, 32), blk, 0, stream>>>(xb, wvb, nullptr, Yv, 4096, 1024, 1024);
    yv_tr<<<dim3(16, 64), blk, 0, stream>>>(Yv, YvT);

    // scores + rel-pos skew (MFMA), batch-softmax, PV (MFMA)
    qk_skew_mfma<<<dim3(16, 16, 64), blk, 0, stream>>>(Yq, Yk, relwT, sc);
    softmax_b<<<dim3(32768), blk, 0, stream>>>(sc);
    pv_mfma<<<dim3(16, 64), blk, 0, stream>>>(sc, YvT, O);

    // h1 = LN(x + attn_out)
    add_ln<1,0><<<dim3(4096), blk, 0, stream>>>(x, O, g1, be1, h1);

    // FFN weights -> bf16 (scores region dead after pv)
    cvt_f32_bf16<<<dim3(M4 / 1024), blk, 0, stream>>>(w1, w1b, M4);
    cvt_f32_bf16<<<dim3(M4 / 1024), blk, 0, stream>>>(w2, w2b, M4);

    // FFN (MFMA)
    mfma_gemm<1,0,1><<<dim3(32, 32), blk, 0, stream>>>(h1, w1b, b1, ffn1, 4096, 4096, 1024);
    mfma_gemm<0,1,1><<<dim3(8, 32), blk, 0, stream>>>(ffn1, w2b, b2, ffn2, 4096, 1024, 4096);

    // out = LN(h1 + ffn) -> f32
    add_ln<0,1><<<dim3(4096), blk, 0, stream>>>(h1, ffn2, g2, be2, (float*)d_out);
}